// Round 1
// baseline (504.283 us; speedup 1.0000x reference)
//
#include <hip/hip_runtime.h>
#include <math.h>

// ---------------------------------------------------------------------------
// CapsNet forward:
//   h = squash(relu(conv3x3(x,Wb)+bb), axis=C)          [128,64,8,8]
//   3x cap_layer(W1[4096,64], b_basic[i])  64->64 caps   [128,64,8,8]
//   1x cap_layer(W2[640,64],  b_cls)       ->[128,10,64] (output)
// All fp32 (no fp32 MFMA on CDNA4 -> VALU).
// ---------------------------------------------------------------------------

// Conv 3x3 SAME + bias + ReLU + squash over channel dim. One block per sample.
__global__ __launch_bounds__(256) void conv_squash_kernel(
    const float* __restrict__ x,   // [128,64,8,8]
    const float* __restrict__ Wb,  // [64,64,3,3]
    const float* __restrict__ bb,  // [64]
    float* __restrict__ h)         // [128,64,64]
{
    __shared__ float xs[6400];   // [ic][10*10] zero-padded image
    __shared__ float hs[4096];   // [oc][hw]
    __shared__ float scl[64];
    const int b = blockIdx.x;
    const int t = threadIdx.x;

    for (int idx = t; idx < 6400; idx += 256) xs[idx] = 0.f;
    __syncthreads();
    #pragma unroll
    for (int k = 0; k < 4; ++k) {
        int idx4 = t + k * 256;              // 1024 float4 = 4096 floats
        float4 v = *(const float4*)&x[(size_t)b * 4096 + idx4 * 4];
        int e0 = idx4 * 4;
        int c  = e0 >> 6;
        int hw = e0 & 63;
        int r = hw >> 3, cc = hw & 7;
        float* xp = &xs[c * 100 + (r + 1) * 10 + (cc + 1)];
        xp[0] = v.x; xp[1] = v.y; xp[2] = v.z; xp[3] = v.w;
    }
    __syncthreads();

    const int oc = t >> 2;       // 0..63
    const int hg = t & 3;        // 16 hw positions per thread
    float acc[16];
    #pragma unroll
    for (int k = 0; k < 16; ++k) acc[k] = 0.f;

    const float* wp = Wb + (size_t)oc * 64 * 9;
    for (int ic = 0; ic < 64; ++ic) {
        float w[9];
        #pragma unroll
        for (int j = 0; j < 9; ++j) w[j] = wp[ic * 9 + j];
        const float* xr = &xs[ic * 100];
        #pragma unroll
        for (int k = 0; k < 16; ++k) {
            int hw = hg * 16 + k;
            int r = hw >> 3, cc = hw & 7;
            int p0 = r * 10 + cc;    // padded coords: (r+kh)*10 + (cc+kw)
            float a = acc[k];
            a = fmaf(w[0], xr[p0],      a);
            a = fmaf(w[1], xr[p0 + 1],  a);
            a = fmaf(w[2], xr[p0 + 2],  a);
            a = fmaf(w[3], xr[p0 + 10], a);
            a = fmaf(w[4], xr[p0 + 11], a);
            a = fmaf(w[5], xr[p0 + 12], a);
            a = fmaf(w[6], xr[p0 + 20], a);
            a = fmaf(w[7], xr[p0 + 21], a);
            a = fmaf(w[8], xr[p0 + 22], a);
            acc[k] = a;
        }
    }
    float bias = bb[oc];
    #pragma unroll
    for (int k = 0; k < 16; ++k) {
        float v = acc[k] + bias;
        v = v > 0.f ? v : 0.f;                 // ReLU
        hs[oc * 64 + hg * 16 + k] = v;
    }
    __syncthreads();
    if (t < 64) {                               // squash scale per hw
        float n2 = 0.f;
        for (int c = 0; c < 64; ++c) { float v = hs[c * 64 + t]; n2 = fmaf(v, v, n2); }
        scl[t] = (n2 / (1.f + n2)) * rsqrtf(n2 + 1e-8f);
    }
    __syncthreads();
    #pragma unroll
    for (int k = 0; k < 4; ++k) {
        int idx4 = t + k * 256;
        int e0 = idx4 * 4;
        int hw0 = e0 & 63;
        float4 o;
        o.x = hs[e0 + 0] * scl[hw0 + 0];
        o.y = hs[e0 + 1] * scl[hw0 + 1];
        o.z = hs[e0 + 2] * scl[hw0 + 2];
        o.w = hs[e0 + 3] * scl[hw0 + 3];
        *(float4*)&h[(size_t)b * 4096 + e0] = o;
    }
}

// pred[b][o][i][d] = sum_c W[o*64+d][c] * h[b][c][i] + bias[o*64+d]
// One block per (chunk-local b, o): 64x64 output tile, 4x4 per thread.
__global__ __launch_bounds__(256) void pred_kernel(
    const float* __restrict__ h,     // [128,64,64]
    const float* __restrict__ W,     // [O*64,64]
    const float* __restrict__ bias,  // [O*64]
    float* __restrict__ pred,        // [CB,O,64,64]
    int O, int b0)
{
    __shared__ float hA[4096];   // [c][i]
    __shared__ float wT[4096];   // [c][d]
    const int blk = blockIdx.x;
    const int b = blk / O;
    const int o = blk % O;
    const int t = threadIdx.x;

    const float* hp = h + (size_t)(b0 + b) * 4096;
    const float* wp = W + (size_t)o * 4096;
    #pragma unroll
    for (int k = 0; k < 4; ++k) {
        int idx4 = t + k * 256;
        *(float4*)&hA[idx4 * 4] = *(const float4*)&hp[idx4 * 4];
        float4 wv = *(const float4*)&wp[idx4 * 4];
        int e0 = idx4 * 4;
        int d  = e0 >> 6;
        int c0 = e0 & 63;
        wT[(c0 + 0) * 64 + d] = wv.x;
        wT[(c0 + 1) * 64 + d] = wv.y;
        wT[(c0 + 2) * 64 + d] = wv.z;
        wT[(c0 + 3) * 64 + d] = wv.w;
    }
    __syncthreads();

    const int i0 = (t >> 4) * 4;
    const int d0 = (t & 15) * 4;
    float acc[4][4];
    #pragma unroll
    for (int ii = 0; ii < 4; ++ii)
        #pragma unroll
        for (int jj = 0; jj < 4; ++jj) acc[ii][jj] = 0.f;

    #pragma unroll 8
    for (int c = 0; c < 64; ++c) {
        float4 a4 = *(float4*)&hA[c * 64 + i0];
        float4 w4 = *(float4*)&wT[c * 64 + d0];
        float av[4] = {a4.x, a4.y, a4.z, a4.w};
        float wv[4] = {w4.x, w4.y, w4.z, w4.w};
        #pragma unroll
        for (int ii = 0; ii < 4; ++ii)
            #pragma unroll
            for (int jj = 0; jj < 4; ++jj)
                acc[ii][jj] = fmaf(av[ii], wv[jj], acc[ii][jj]);
    }

    float4 bv = *(const float4*)&bias[(size_t)o * 64 + d0];
    float bvv[4] = {bv.x, bv.y, bv.z, bv.w};
    float* pp = pred + ((size_t)b * O + o) * 4096;
    #pragma unroll
    for (int ii = 0; ii < 4; ++ii) {
        float4 ov;
        ov.x = acc[ii][0] + bvv[0];
        ov.y = acc[ii][1] + bvv[1];
        ov.z = acc[ii][2] + bvv[2];
        ov.w = acc[ii][3] + bvv[3];
        *(float4*)&pp[(i0 + ii) * 64 + d0] = ov;
    }
}

// c = softmax over o of blog[b][o][i]. One block per chunk-local sample.
__global__ __launch_bounds__(256) void softmax_kernel(
    const float* __restrict__ bsrc,  // [CB,O,64] (already chunk-offset)
    float* __restrict__ cbuf,        // [CB,O,64]
    int O)
{
    __shared__ float e[4096];
    __shared__ float rden[64];
    const int b = blockIdx.x;
    const int t = threadIdx.x;
    const int n = O * 64;
    const float* bp = bsrc + (size_t)b * n;
    for (int idx = t; idx < n; idx += 256) e[idx] = expf(bp[idx]);
    __syncthreads();
    if (t < 64) {
        float s = 0.f;
        for (int o = 0; o < O; ++o) s += e[o * 64 + t];
        rden[t] = 1.f / s;
    }
    __syncthreads();
    float* cp = cbuf + (size_t)b * n;
    for (int idx = t; idx < n; idx += 256) cp[idx] = e[idx] * rden[idx & 63];
}

// One routing iteration for one (b,o): s = sum_i c_i * pred[i,:],
// v = squash(s), then either db-update of logits or write v out.
// mode 0: bdst = bsrc + (v . pred[i,:])
// mode 1: h_next[b][d][o] = v[d]   (non-final layer output, transposed)
// mode 2: out[b][o][d] = v[d]      (final layer output)
__global__ __launch_bounds__(64) void route_kernel(
    const float* __restrict__ pred,  // [CB,O,64,64]
    const float* __restrict__ cbuf,  // [CB,O,64]
    const float* __restrict__ bsrc,  // [CB,O,64] or chunk-offset input
    float* __restrict__ bdst,        // [CB,O,64]
    float* __restrict__ vout,
    int O, int b0, int mode)
{
    __shared__ float pl[64 * 65];    // [i][d], stride 65 kills bank conflicts
    __shared__ float cl[64];
    __shared__ float vl[64];
    const int blk = blockIdx.x;
    const int b = blk / O;
    const int o = blk % O;
    const int t = threadIdx.x;

    const float* pp = pred + ((size_t)b * O + o) * 4096;
    #pragma unroll
    for (int k = 0; k < 16; ++k) {
        int idx4 = t + k * 64;
        float4 pv = *(const float4*)&pp[idx4 * 4];
        int e0 = idx4 * 4;
        int i = e0 >> 6;
        int col = e0 & 63;
        float* dp = &pl[i * 65 + col];
        dp[0] = pv.x; dp[1] = pv.y; dp[2] = pv.z; dp[3] = pv.w;
    }
    cl[t] = cbuf[((size_t)b * O + o) * 64 + t];
    __syncthreads();

    // s[d=t] = sum_i c[i] * pred[i][t]
    float s = 0.f;
    #pragma unroll 16
    for (int i = 0; i < 64; ++i) s = fmaf(cl[i], pl[i * 65 + t], s);

    float n2 = s * s;
    #pragma unroll
    for (int off = 32; off; off >>= 1) n2 += __shfl_xor(n2, off, 64);
    float v = s * (n2 / (1.f + n2)) * rsqrtf(n2 + 1e-8f);

    if (mode == 0) {
        vl[t] = v;
        __syncthreads();
        // db[i=t] = sum_d v[d] * pred[t][d]
        float a = 0.f;
        #pragma unroll 16
        for (int d = 0; d < 64; ++d) a = fmaf(vl[d], pl[t * 65 + d], a);
        size_t idx = ((size_t)b * O + o) * 64 + t;
        bdst[idx] = bsrc[idx] + a;
    } else if (mode == 1) {
        vout[((size_t)(b0 + b) * 64 + t) * 64 + o] = v;   // [b][d][o]
    } else {
        vout[((size_t)(b0 + b) * O + o) * 64 + t] = v;    // [b][o][d]
    }
}

extern "C" void kernel_launch(void* const* d_in, const int* in_sizes, int n_in,
                              void* d_out, int out_size, void* d_ws, size_t ws_size,
                              hipStream_t stream) {
    const float* x       = (const float*)d_in[0];
    const float* Wb      = (const float*)d_in[1];
    const float* bb      = (const float*)d_in[2];
    const float* W1      = (const float*)d_in[3];
    const float* b1      = (const float*)d_in[4];
    const float* W2      = (const float*)d_in[5];
    const float* b2      = (const float*)d_in[6];
    const float* b_basic = (const float*)d_in[7];   // [3,128,64,64]
    const float* b_cls   = (const float*)d_in[8];   // [128,10,64]
    float* out = (float*)d_out;

    const int BS = 128;
    const size_t HN = (size_t)BS * 4096;   // h elements

    // choose batch chunk so workspace fits
    int CB = 128;
    const size_t fixed = 2 * HN * sizeof(float);
    while (CB > 1) {
        size_t need = fixed + ((size_t)CB * 64 * 4096 + 2 * (size_t)CB * 4096) * sizeof(float);
        if (need <= ws_size) break;
        CB >>= 1;
    }

    float* h0   = (float*)d_ws;
    float* h1   = h0 + HN;
    float* pred = h1 + HN;
    float* blog = pred + (size_t)CB * 64 * 4096;
    float* cbuf = blog + (size_t)CB * 4096;

    conv_squash_kernel<<<BS, 256, 0, stream>>>(x, Wb, bb, h0);

    const float* hin = h0;
    float* hout = h1;
    for (int L = 0; L < 3; ++L) {
        const float* bsrc0 = b_basic + (size_t)L * BS * 4096;
        for (int cb = 0; cb < BS; cb += CB) {
            const float* bsl = bsrc0 + (size_t)cb * 4096;
            pred_kernel<<<CB * 64, 256, 0, stream>>>(hin, W1, b1, pred, 64, cb);
            softmax_kernel<<<CB, 256, 0, stream>>>(bsl, cbuf, 64);
            route_kernel<<<CB * 64, 64, 0, stream>>>(pred, cbuf, bsl, blog, nullptr, 64, cb, 0);
            softmax_kernel<<<CB, 256, 0, stream>>>(blog, cbuf, 64);
            route_kernel<<<CB * 64, 64, 0, stream>>>(pred, cbuf, blog, blog, nullptr, 64, cb, 0);
            softmax_kernel<<<CB, 256, 0, stream>>>(blog, cbuf, 64);
            route_kernel<<<CB * 64, 64, 0, stream>>>(pred, cbuf, nullptr, nullptr, hout, 64, cb, 1);
        }
        const float* tmp = hin; hin = hout; hout = (float*)tmp;
    }
    // final layer: O = 10
    for (int cb = 0; cb < BS; cb += CB) {
        const float* bsl = b_cls + (size_t)cb * 640;
        pred_kernel<<<CB * 10, 256, 0, stream>>>(hin, W2, b2, pred, 10, cb);
        softmax_kernel<<<CB, 256, 0, stream>>>(bsl, cbuf, 10);
        route_kernel<<<CB * 10, 64, 0, stream>>>(pred, cbuf, bsl, blog, nullptr, 10, cb, 0);
        softmax_kernel<<<CB, 256, 0, stream>>>(blog, cbuf, 10);
        route_kernel<<<CB * 10, 64, 0, stream>>>(pred, cbuf, blog, blog, nullptr, 10, cb, 0);
        softmax_kernel<<<CB, 256, 0, stream>>>(blog, cbuf, 10);
        route_kernel<<<CB * 10, 64, 0, stream>>>(pred, cbuf, nullptr, nullptr, out, 10, cb, 2);
    }
}

// Round 2
// 402.037 us; speedup vs baseline: 1.2543x; 1.2543x over previous
//
#include <hip/hip_runtime.h>
#include <math.h>

// ---------------------------------------------------------------------------
// CapsNet forward, fully fused:
//   conv3x3+ReLU+squash  ->  3x cap_layer(64->64)  ->  cap_layer(->10)  all in
//   ONE routing kernel (block = sample), pred never materialized:
//     s  = W_o . y  + bias_o * sum(c)     with y = sum_i c_i h[:,i]
//     db = u . h    + v.bias_o            with u = v . W_o
// ---------------------------------------------------------------------------

// Conv 3x3 SAME + bias + ReLU + squash over channel dim. One block per sample.
__global__ __launch_bounds__(256) void conv_squash_kernel(
    const float* __restrict__ x,   // [128,64,8,8]
    const float* __restrict__ Wb,  // [64,64,3,3]
    const float* __restrict__ bb,  // [64]
    float* __restrict__ h)         // [128,64,64]
{
    __shared__ float xs[6400];   // [ic][10*10] zero-padded image
    __shared__ float hs[4096];   // [oc][hw]
    __shared__ float scl[64];
    const int b = blockIdx.x;
    const int t = threadIdx.x;

    for (int idx = t; idx < 6400; idx += 256) xs[idx] = 0.f;
    __syncthreads();
    #pragma unroll
    for (int k = 0; k < 4; ++k) {
        int idx4 = t + k * 256;
        float4 v = *(const float4*)&x[(size_t)b * 4096 + idx4 * 4];
        int e0 = idx4 * 4;
        int c  = e0 >> 6;
        int hw = e0 & 63;
        int r = hw >> 3, cc = hw & 7;
        float* xp = &xs[c * 100 + (r + 1) * 10 + (cc + 1)];
        xp[0] = v.x; xp[1] = v.y; xp[2] = v.z; xp[3] = v.w;
    }
    __syncthreads();

    const int oc = t >> 2;
    const int hg = t & 3;
    float acc[16];
    #pragma unroll
    for (int k = 0; k < 16; ++k) acc[k] = 0.f;

    const float* wp = Wb + (size_t)oc * 64 * 9;
    for (int ic = 0; ic < 64; ++ic) {
        float w[9];
        #pragma unroll
        for (int j = 0; j < 9; ++j) w[j] = wp[ic * 9 + j];
        const float* xr = &xs[ic * 100];
        #pragma unroll
        for (int k = 0; k < 16; ++k) {
            int hw = hg * 16 + k;
            int r = hw >> 3, cc = hw & 7;
            int p0 = r * 10 + cc;
            float a = acc[k];
            a = fmaf(w[0], xr[p0],      a);
            a = fmaf(w[1], xr[p0 + 1],  a);
            a = fmaf(w[2], xr[p0 + 2],  a);
            a = fmaf(w[3], xr[p0 + 10], a);
            a = fmaf(w[4], xr[p0 + 11], a);
            a = fmaf(w[5], xr[p0 + 12], a);
            a = fmaf(w[6], xr[p0 + 20], a);
            a = fmaf(w[7], xr[p0 + 21], a);
            a = fmaf(w[8], xr[p0 + 22], a);
            acc[k] = a;
        }
    }
    float bias = bb[oc];
    #pragma unroll
    for (int k = 0; k < 16; ++k) {
        float v = acc[k] + bias;
        v = v > 0.f ? v : 0.f;
        hs[oc * 64 + hg * 16 + k] = v;
    }
    __syncthreads();
    if (t < 64) {
        float n2 = 0.f;
        for (int c = 0; c < 64; ++c) { float v = hs[c * 64 + t]; n2 = fmaf(v, v, n2); }
        scl[t] = (n2 / (1.f + n2)) * rsqrtf(n2 + 1e-8f);
    }
    __syncthreads();
    #pragma unroll
    for (int k = 0; k < 4; ++k) {
        int idx4 = t + k * 256;
        int e0 = idx4 * 4;
        int hw0 = e0 & 63;
        float4 o;
        o.x = hs[e0 + 0] * scl[hw0 + 0];
        o.y = hs[e0 + 1] * scl[hw0 + 1];
        o.z = hs[e0 + 2] * scl[hw0 + 2];
        o.w = hs[e0 + 3] * scl[hw0 + 3];
        *(float4*)&h[(size_t)b * 4096 + e0] = o;
    }
}

// Fused routing for all 4 cap layers. One block per sample, 1024 threads.
// LDS (64 KB exactly):
//   HTa/HTb : h as [i][c] (k-major for both GEMV phases), ping-pong per layer
//   BL      : routing logits [o][i]
//   CC      : softmax c [o][i]; rows double as per-o scratch (y row, then u row)
//   PP/RD   : softmax partials / reciprocal denominators, overlaid on HTn
//             (HTn rows 0..16 are dead during the softmax phases)
__global__ __launch_bounds__(1024) void caps_fused(
    const float* __restrict__ h0,
    const float* __restrict__ W1, const float* __restrict__ b1,
    const float* __restrict__ W2, const float* __restrict__ b2,
    const float* __restrict__ b_basic, const float* __restrict__ b_cls,
    float* __restrict__ out)
{
    __shared__ float HTa[4096];
    __shared__ float HTb[4096];
    __shared__ float BL[4096];
    __shared__ float CC[4096];

    const int b    = blockIdx.x;
    const int t    = threadIdx.x;
    const int wv   = t >> 6;      // wave 0..15
    const int lane = t & 63;
    const int Q    = lane & 15;   // c-quad / slot index
    const int G    = lane >> 4;   // k-split group

    // initial transposed load: HTa[i][c] = h0[b][c][i]
    {
        float4 v = *(const float4*)&h0[(size_t)b * 4096 + t * 4];
        int c  = t >> 4;
        int i0 = (t & 15) * 4;
        HTa[(i0 + 0) * 64 + c] = v.x;
        HTa[(i0 + 1) * 64 + c] = v.y;
        HTa[(i0 + 2) * 64 + c] = v.z;
        HTa[(i0 + 3) * 64 + c] = v.w;
    }

    for (int L = 0; L < 4; ++L) {
        const bool fin = (L == 3);
        const int O = fin ? 10 : 64;
        const float* W    = fin ? W2 : W1;
        const float* bias = fin ? b2 : b1;
        float* HT  = (L & 1) ? HTb : HTa;
        float* HTn = (L & 1) ? HTa : HTb;
        float* PP  = HTn;          // [16][64] overlay
        float* RD  = HTn + 1024;   // [64]    overlay

        __syncthreads();   // prev layer fully done; HT (=prev HTn) ready
        if (fin) {
            if (t < 160) *(float4*)&BL[t * 4] = *(const float4*)&b_cls[(size_t)b * 640 + t * 4];
        } else {
            *(float4*)&BL[t * 4] =
                *(const float4*)&b_basic[(((size_t)L * 128 + b) << 12) + t * 4];
        }

        for (int it = 0; it < 3; ++it) {
            __syncthreads();   // A: BL ready (init or db), prev-iter LDS quiesced
            // -- softmax over o (pass 1: exp + per-wave partial column sums) --
            float part = 0.f;
            #pragma unroll
            for (int r = 0; r < 4; ++r) {
                int o = 4 * wv + r;
                if (o < O) {
                    float e = expf(BL[o * 64 + lane]);
                    CC[o * 64 + lane] = e;
                    part += e;
                }
            }
            PP[wv * 64 + lane] = part;
            __syncthreads();   // B
            if (wv == 0) {
                float den = 0.f;
                #pragma unroll
                for (int w2 = 0; w2 < 16; ++w2) den += PP[w2 * 64 + lane];
                RD[lane] = 1.f / den;
            }
            __syncthreads();   // C
            {
                float rr0 = RD[lane];
                #pragma unroll
                for (int rr = 0; rr < 4; ++rr) {
                    int o = 4 * wv + rr;
                    if (o < O) CC[o * 64 + lane] *= rr0;
                }
            }
            __syncthreads();   // D: CC complete; HT stable from here on

            // -- Y: y[o,c] = sum_i c[o,i] h[c,i], 4 o's per wave, k-split on i --
            float yy[4][4];
            float sc[4];
            #pragma unroll
            for (int a = 0; a < 4; ++a) {
                sc[a] = 0.f;
                #pragma unroll
                for (int j2 = 0; j2 < 4; ++j2) yy[a][j2] = 0.f;
            }
            if (wv < O) {
                #pragma unroll 4
                for (int k = 0; k < 16; ++k) {
                    int i = G * 16 + k;
                    float4 h4 = *(float4*)&HT[i * 64 + 4 * Q];
                    #pragma unroll
                    for (int oo = 0; oo < 4; ++oo) {
                        int o = wv + 16 * oo;
                        if (o < O) {
                            float cv = CC[o * 64 + i];
                            yy[oo][0] = fmaf(cv, h4.x, yy[oo][0]);
                            yy[oo][1] = fmaf(cv, h4.y, yy[oo][1]);
                            yy[oo][2] = fmaf(cv, h4.z, yy[oo][2]);
                            yy[oo][3] = fmaf(cv, h4.w, yy[oo][3]);
                            sc[oo] += cv;
                        }
                    }
                }
                #pragma unroll
                for (int m = 16; m <= 32; m <<= 1) {
                    #pragma unroll
                    for (int oo = 0; oo < 4; ++oo) {
                        yy[oo][0] += __shfl_xor(yy[oo][0], m, 64);
                        yy[oo][1] += __shfl_xor(yy[oo][1], m, 64);
                        yy[oo][2] += __shfl_xor(yy[oo][2], m, 64);
                        yy[oo][3] += __shfl_xor(yy[oo][3], m, 64);
                        sc[oo]    += __shfl_xor(sc[oo],    m, 64);
                    }
                }
                if (G == 0) {
                    #pragma unroll
                    for (int oo = 0; oo < 4; ++oo) {
                        int o = wv + 16 * oo;
                        if (o < O) {
                            float4 w4;
                            w4.x = yy[oo][0]; w4.y = yy[oo][1];
                            w4.z = yy[oo][2]; w4.w = yy[oo][3];
                            *(float4*)&CC[o * 64 + 4 * Q] = w4;   // y row -> scratch
                        }
                    }
                }
            }

            // -- per-o: S = W_o.y + bias*sumc, squash, u = v.W_o, db update --
            #pragma unroll 1
            for (int oo = 0; oo < 4; ++oo) {
                int o = wv + 16 * oo;
                if (o >= O) break;
                const float* Wo = W + ((size_t)(o * 64 + lane) << 6);
                float s = 0.f;
                #pragma unroll
                for (int k = 0; k < 16; ++k) {
                    float4 w4 = *(const float4*)&Wo[4 * k];
                    float4 y4 = *(const float4*)&CC[o * 64 + 4 * k];  // broadcast
                    s = fmaf(w4.x, y4.x, s);
                    s = fmaf(w4.y, y4.y, s);
                    s = fmaf(w4.z, y4.z, s);
                    s = fmaf(w4.w, y4.w, s);
                }
                float bb2 = bias[o * 64 + lane];
                s = fmaf(bb2, sc[oo], s);
                float n2 = s * s;
                #pragma unroll
                for (int m = 1; m < 64; m <<= 1) n2 += __shfl_xor(n2, m, 64);
                float v = s * (n2 / (1.f + n2)) * rsqrtf(n2 + 1e-8f);
                HTn[o * 64 + lane] = v;                 // v row (= next-layer HT)
                if (fin && it == 2) out[((size_t)b * 10 + o) * 64 + lane] = v;
                if (it < 2) {
                    float vd = v * bb2;
                    #pragma unroll
                    for (int m = 1; m < 64; m <<= 1) vd += __shfl_xor(vd, m, 64);
                    // u[o,c]: k-split over d; W read is lane-coalesced b128
                    float u4x = 0.f, u4y = 0.f, u4z = 0.f, u4w = 0.f;
                    #pragma unroll 4
                    for (int k = 0; k < 16; ++k) {
                        int d = G * 16 + k;
                        float vv = HTn[o * 64 + d];     // broadcast
                        float4 w4 = *(const float4*)&W[((size_t)(o * 64 + d) << 6) + 4 * Q];
                        u4x = fmaf(vv, w4.x, u4x);
                        u4y = fmaf(vv, w4.y, u4y);
                        u4z = fmaf(vv, w4.z, u4z);
                        u4w = fmaf(vv, w4.w, u4w);
                    }
                    #pragma unroll
                    for (int m = 16; m <= 32; m <<= 1) {
                        u4x += __shfl_xor(u4x, m, 64);
                        u4y += __shfl_xor(u4y, m, 64);
                        u4z += __shfl_xor(u4z, m, 64);
                        u4w += __shfl_xor(u4w, m, 64);
                    }
                    if (G == 0) {
                        float4 uu; uu.x = u4x; uu.y = u4y; uu.z = u4z; uu.w = u4w;
                        *(float4*)&CC[o * 64 + 4 * Q] = uu;   // u row -> scratch
                    }
                    // db[o,i=lane] = sum_c u[c] h[c,i]; per-lane slot rotation
                    float acc2 = 0.f;
                    #pragma unroll
                    for (int k = 0; k < 16; ++k) {
                        int cq = k ^ Q;
                        float4 uu = *(float4*)&CC[o * 64 + 4 * cq];
                        float4 hh = *(float4*)&HT[lane * 64 + 4 * cq];
                        acc2 = fmaf(uu.x, hh.x, acc2);
                        acc2 = fmaf(uu.y, hh.y, acc2);
                        acc2 = fmaf(uu.z, hh.z, acc2);
                        acc2 = fmaf(uu.w, hh.w, acc2);
                    }
                    BL[o * 64 + lane] += acc2 + vd;
                }
            }
        }
    }
}

extern "C" void kernel_launch(void* const* d_in, const int* in_sizes, int n_in,
                              void* d_out, int out_size, void* d_ws, size_t ws_size,
                              hipStream_t stream) {
    const float* x       = (const float*)d_in[0];
    const float* Wb      = (const float*)d_in[1];
    const float* bb      = (const float*)d_in[2];
    const float* W1      = (const float*)d_in[3];
    const float* b1      = (const float*)d_in[4];
    const float* W2      = (const float*)d_in[5];
    const float* b2      = (const float*)d_in[6];
    const float* b_basic = (const float*)d_in[7];
    const float* b_cls   = (const float*)d_in[8];
    float* out = (float*)d_out;

    float* h0 = (float*)d_ws;   // [128,64,64]

    conv_squash_kernel<<<128, 256, 0, stream>>>(x, Wb, bb, h0);
    caps_fused<<<128, 1024, 0, stream>>>(h0, W1, b1, W2, b2, b_basic, b_cls, out);
}